// Round 4
// baseline (780.077 us; speedup 1.0000x reference)
//
#include <hip/hip_runtime.h>

typedef __attribute__((ext_vector_type(8))) short s8_t;   // 8 bf16 (4 VGPRs) MFMA frag
typedef __attribute__((ext_vector_type(4))) float f4_t;   // MFMA accumulator

#define NBATCH 256
#define NCH    128
#define NT     4096
#define NF     64
#define TT     128            // time tile
#define CHUNKS 4              // time-split per batch (grid = 256*4)
#define CT     (NT / CHUNKS)  // 1024 timesteps per block
#define NIT    (CT / TT)      // 8 tiles per block
#define LDSK   (TT + 8)       // padded LDS row stride (bf16 elems)
#define CHEB_D 20

static __device__ __forceinline__ unsigned short f32_bf16(float f) {
    unsigned int u = __float_as_uint(f);
    return (unsigned short)((u + 0x7FFFu + ((u >> 16) & 1u)) >> 16);  // RNE
}
static __device__ __forceinline__ float bf16_f32(unsigned short h) {
    return __uint_as_float(((unsigned int)h) << 16);
}

// ---------------- Kernel 1: partial Gram G_p = X_chunk X_chunk^T (bf16 MFMA) ----------
// Grid 1024 = 256 batches x 4 time-chunks. 512 threads (8 waves), 2 blocks/CU.
__global__ __launch_bounds__(512, 4)
void k_gram(const float* __restrict__ x, float* __restrict__ gws, float* __restrict__ sxws) {
    __shared__ __align__(16) unsigned short xl[2][NCH * LDSK];  // 69632 B double-buffered
    __shared__ float red[512];

    const int tid  = threadIdx.x;
    const int lane = tid & 63;
    const int wv   = tid >> 6;       // wave id 0..7
    const int bid  = blockIdx.x;     // = b*4 + chunk
    const int b    = bid >> 2;
    const int chnk = bid & 3;
    const int lrow16 = tid >> 5;     // 0..15 (load row group)
    const int lchunk = tid & 31;     // 0..31 (load column chunk)

    const float* xb = x + (size_t)b * ((size_t)NCH * NT) + chnk * CT;

    // wave wv owns G rows arow0..arow0+31, cols bcol0..bcol0+63
    const int arow0 = (wv & 3) * 32;
    const int bcol0 = (wv >> 2) * 64;
    const int lrow  = lane & 15;
    const int koff  = (lane >> 4) * 8;

    f4_t acc[2][4];
    #pragma unroll
    for (int i = 0; i < 2; ++i)
        #pragma unroll
        for (int j = 0; j < 4; ++j)
            acc[i][j] = (f4_t){0.f, 0.f, 0.f, 0.f};

    float sxp = 0.f;
    float4 ld[8];

    // prologue: stage tile 0
    #pragma unroll
    for (int j = 0; j < 8; ++j) {
        const int r = j * 16 + lrow16;
        ld[j] = *(const float4*)(xb + (size_t)r * NT + lchunk * 4);
    }
    #pragma unroll
    for (int j = 0; j < 8; ++j) {
        const int r = j * 16 + lrow16;
        ushort4 h;
        h.x = f32_bf16(ld[j].x); h.y = f32_bf16(ld[j].y);
        h.z = f32_bf16(ld[j].z); h.w = f32_bf16(ld[j].w);
        *(ushort4*)&xl[0][r * LDSK + lchunk * 4] = h;
    }
    __syncthreads();

    for (int it = 0; it < NIT; ++it) {
        const int cur = it & 1;
        if (it + 1 < NIT) {   // issue next tile's loads early (hide under MFMA)
            const int t0 = (it + 1) * TT;
            #pragma unroll
            for (int j = 0; j < 8; ++j) {
                const int r = j * 16 + lrow16;
                ld[j] = *(const float4*)(xb + (size_t)r * NT + t0 + lchunk * 4);
            }
        }
        const unsigned short* bufc = xl[cur];
        #pragma unroll
        for (int ks = 0; ks < TT / 32; ++ks) {
            const int k0 = ks * 32 + koff;
            const s8_t af0 = *(const s8_t*)&bufc[(arow0 + lrow) * LDSK + k0];
            const s8_t af1 = *(const s8_t*)&bufc[(arow0 + 16 + lrow) * LDSK + k0];
            #pragma unroll
            for (int cb = 0; cb < 4; ++cb) {
                const s8_t bf = *(const s8_t*)&bufc[(bcol0 + cb * 16 + lrow) * LDSK + k0];
                acc[0][cb] = __builtin_amdgcn_mfma_f32_16x16x32_bf16(af0, bf, acc[0][cb], 0, 0, 0);
                acc[1][cb] = __builtin_amdgcn_mfma_f32_16x16x32_bf16(af1, bf, acc[1][cb], 0, 0, 0);
            }
        }
        {   // channel-sum partial: thread -> row tid>>2, quarter tid&3
            const unsigned short* rp = &bufc[(tid >> 2) * LDSK + (tid & 3) * 32];
            float s = 0.f;
            #pragma unroll
            for (int q = 0; q < 4; ++q) {
                s8_t v = *(const s8_t*)&rp[q * 8];
                #pragma unroll
                for (int e = 0; e < 8; ++e)
                    s += bf16_f32((unsigned short)v[e]);
            }
            sxp += s;
        }
        if (it + 1 < NIT) {   // convert + stage into the other buffer
            #pragma unroll
            for (int j = 0; j < 8; ++j) {
                const int r = j * 16 + lrow16;
                ushort4 h;
                h.x = f32_bf16(ld[j].x); h.y = f32_bf16(ld[j].y);
                h.z = f32_bf16(ld[j].z); h.w = f32_bf16(ld[j].w);
                *(ushort4*)&xl[cur ^ 1][r * LDSK + lchunk * 4] = h;
            }
        }
        __syncthreads();
    }

    // store partial G  (C/D layout: col = lane&15, row = (lane>>4)*4 + reg)
    float* gb = gws + ((size_t)bid << 14);
    const int lrow4 = (lane >> 4) * 4;
    const int lcol  = lane & 15;
    #pragma unroll
    for (int i = 0; i < 2; ++i) {
        const int rbase = arow0 + i * 16 + lrow4;
        #pragma unroll
        for (int cb = 0; cb < 4; ++cb) {
            const int col = bcol0 + cb * 16 + lcol;
            #pragma unroll
            for (int reg = 0; reg < 4; ++reg)
                gb[(size_t)(rbase + reg) * NCH + col] = acc[i][cb][reg];
        }
    }
    red[tid] = sxp;
    __syncthreads();
    if (tid < NCH)
        sxws[bid * NCH + tid] = red[tid * 4] + red[tid * 4 + 1] + red[tid * 4 + 2] + red[tid * 4 + 3];
}

// ---------------- Kernel 2: cov build + matrix log via Chebyshev-Clenshaw + triu vec ----
// 256 blocks x 512 threads (8 waves/CU, 2/SIMD). VALU-bound 64x64 f32 matmuls.
__global__ __launch_bounds__(512, 2)
void k_logm(const float* __restrict__ gws, const float* __restrict__ sxws,
            const float* __restrict__ wmat, float* __restrict__ out) {
    __shared__ __align__(16) float lds[33032];
    float* sG   = lds;           // [128][128] summed Gram (dead after M1)
    float* sC0  = lds;           // [64][64] cov0   (aliases dead G)
    float* sU   = lds + 4096;    // [64][64] A then normalized arg (in place)
    float* sB0  = lds + 8192;    // Clenshaw ping
    float* sB1  = lds + 12288;   // Clenshaw pong
    float* sWt  = lds + 16384;   // [128][64] W transposed
    float* sM1t = lds + 24576;   // [128][64] (W*G) transposed (also temp W staging)
    float* ssx  = lds + 32768;   // [128]
    float* sp   = lds + 32896;   // [64]  p = W*sx
    float* sred = lds + 32960;   // [64]
    float* sscal= lds + 33024;   // scalars

    const int tid = threadIdx.x;
    const int b   = blockIdx.x;

    // coalesced W load into temp, transposed to sWt after barrier
    for (int i = tid; i < NF * NCH; i += 512) sM1t[i] = wmat[i];
    if (tid < NCH) {   // sum 4 partial channel sums
        const float* sxb = sxws + (size_t)b * 4 * NCH;
        ssx[tid] = sxb[tid] + sxb[NCH + tid] + sxb[2 * NCH + tid] + sxb[3 * NCH + tid];
    }
    {   // sum 4 partial Grams (float4)
        const float4* g0 = (const float4*)(gws + ((size_t)(b * 4 + 0) << 14));
        const float4* g1 = (const float4*)(gws + ((size_t)(b * 4 + 1) << 14));
        const float4* g2 = (const float4*)(gws + ((size_t)(b * 4 + 2) << 14));
        const float4* g3 = (const float4*)(gws + ((size_t)(b * 4 + 3) << 14));
        float4* dst = (float4*)sG;
        for (int i = tid; i < 4096; i += 512) {
            const float4 a = g0[i], c = g1[i], d = g2[i], e = g3[i];
            float4 r;
            r.x = a.x + c.x + d.x + e.x;
            r.y = a.y + c.y + d.y + e.y;
            r.z = a.z + c.z + d.z + e.z;
            r.w = a.w + c.w + d.w + e.w;
            dst[i] = r;
        }
    }
    __syncthreads();
    for (int i = tid; i < NF * NCH; i += 512) {   // transpose: sWt[k*64+f] = W[f][k]
        const int f = i >> 7, k = i & 127;
        sWt[k * 64 + f] = sM1t[i];
    }
    __syncthreads();

    // M1 = W*G (64x128), stored transposed. Thread: 4 f-rows x 4 c-cols.
    {
        const int f0 = (tid >> 5) * 4, c0 = (tid & 31) * 4;
        float a[4][4];
        #pragma unroll
        for (int i = 0; i < 4; ++i)
            #pragma unroll
            for (int j = 0; j < 4; ++j) a[i][j] = 0.f;
        for (int k = 0; k < NCH; ++k) {
            const float4 w4 = *(const float4*)&sWt[k * 64 + f0];
            const float4 g4 = *(const float4*)&sG[k * NCH + c0];
            const float wa[4] = {w4.x, w4.y, w4.z, w4.w};
            const float ga[4] = {g4.x, g4.y, g4.z, g4.w};
            #pragma unroll
            for (int i = 0; i < 4; ++i)
                #pragma unroll
                for (int j = 0; j < 4; ++j)
                    a[i][j] = fmaf(wa[i], ga[j], a[i][j]);
        }
        #pragma unroll
        for (int j = 0; j < 4; ++j) {
            float4 v; v.x = a[0][j]; v.y = a[1][j]; v.z = a[2][j]; v.w = a[3][j];
            *(float4*)&sM1t[(c0 + j) * 64 + f0] = v;
        }
    }
    if (tid < NF) {   // p = W * sx
        float s = 0.f;
        for (int k = 0; k < NCH; ++k) s = fmaf(sWt[k * 64 + tid], ssx[k], s);
        sp[tid] = s;
    }
    __syncthreads();

    // C0 = (M1*W^T - p p^T / T) / (T-1).  Thread: 4 f-rows x 2 g-cols.
    {
        const int f0 = (tid >> 5) * 4, g2 = (tid & 31) * 2;
        float a[4][2];
        #pragma unroll
        for (int i = 0; i < 4; ++i) { a[i][0] = 0.f; a[i][1] = 0.f; }
        for (int k = 0; k < NCH; ++k) {
            const float4 m4 = *(const float4*)&sM1t[k * 64 + f0];
            const float2 w2 = *(const float2*)&sWt[k * 64 + g2];
            const float ma[4] = {m4.x, m4.y, m4.z, m4.w};
            #pragma unroll
            for (int i = 0; i < 4; ++i) {
                a[i][0] = fmaf(ma[i], w2.x, a[i][0]);
                a[i][1] = fmaf(ma[i], w2.y, a[i][1]);
            }
        }
        const float i4096 = 1.f / 4096.f, i4095 = 1.f / 4095.f;
        #pragma unroll
        for (int i = 0; i < 4; ++i)
            #pragma unroll
            for (int j = 0; j < 2; ++j)
                sC0[(f0 + i) * 64 + (g2 + j)] =
                    (a[i][j] - sp[f0 + i] * sp[g2 + j] * i4096) * i4095;
    }
    __syncthreads();

    if (tid == 0) {                        // mu = trace/64
        float s = 0.f;
        for (int i = 0; i < 64; ++i) s += sC0[i * 65];
        sscal[0] = s * (1.f / 64.f);
    }
    __syncthreads();

    const float mu = sscal[0];
    const float dshift = 0.1f * mu + 1e-4f;   // guaranteed lambda_min lower bound
    for (int i = tid; i < 4096; i += 512) {   // A = 0.45(C0+C0^T) + dshift I  -> sU
        const int r = i >> 6, c = i & 63;
        float v = 0.45f * (sC0[r * 64 + c] + sC0[c * 64 + r]);
        if (r == c) v += dshift;
        sU[i] = v;
    }
    __syncthreads();

    if (tid < 64) {                        // Gershgorin: column abs-sums (A symmetric)
        float s = 0.f;
        for (int j = 0; j < 64; ++j) s += fabsf(sU[j * 64 + tid]);
        sred[tid] = s;
    }
    __syncthreads();
    if (tid == 0) {
        float hi = 0.f;
        for (int i = 0; i < 64; ++i) hi = fmaxf(hi, sred[i]);
        const float lo = dshift;
        hi = fmaxf(hi, lo * 1.02f);
        float wsc = (hi - lo) / (hi + lo);
        wsc = fminf(fmaxf(wsc, 1e-6f), 0.999999f);
        const float zz = fmaxf((1.f - sqrtf(fmaxf(1.f - wsc * wsc, 1e-12f))) / wsc, 1e-12f);
        const float mc = 0.5f * (hi + lo);
        sscal[1] = mc;
        sscal[2] = wsc;
        sscal[3] = zz;
        sscal[4] = logf(mc) - log1pf(zz * zz);  // c0 of the Chebyshev series of log
    }
    __syncthreads();

    {   // U = (A/mc - I)/wsc in place, spectrum in [-1,1]
        const float mc = sscal[1], wsc = sscal[2];
        const float inv_mw = 1.f / (mc * wsc);
        const float inv_w  = 1.f / wsc;
        for (int i = tid; i < 4096; i += 512) {
            const int r = i >> 6, c = i & 63;
            float v = sU[i] * inv_mw;
            if (r == c) v -= inv_w;
            sU[i] = v;
        }
    }
    __syncthreads();

    // Matrix Clenshaw: log(x) = c0 + sum_{k=1..D} 2(-1)^{k+1} z^k/k * T_k(u)
    const int f0 = (tid >> 5) * 4, g2 = (tid & 31) * 2;
    const float zc  = sscal[3];
    const float l2z = log2f(zc);
    float rP[4][2], rP2[4][2];
    {
        const float cd = 2.f * ((CHEB_D & 1) ? 1.f : -1.f) *
                         exp2f((float)CHEB_D * l2z) / (float)CHEB_D;
        #pragma unroll
        for (int i = 0; i < 4; ++i)
            #pragma unroll
            for (int j = 0; j < 2; ++j) {
                rP[i][j]  = (f0 + i == g2 + j) ? cd : 0.f;
                rP2[i][j] = 0.f;
            }
        #pragma unroll
        for (int i = 0; i < 4; ++i) {
            float2 v; v.x = rP[i][0]; v.y = rP[i][1];
            *(float2*)&sB0[(f0 + i) * 64 + g2] = v;
        }
    }
    __syncthreads();

    float* bcur = sB0;
    float* bnxt = sB1;
    for (int k = CHEB_D - 1; k >= 1; --k) {
        const float ck = 2.f * ((k & 1) ? 1.f : -1.f) * exp2f((float)k * l2z) / (float)k;
        float a[4][2];
        #pragma unroll
        for (int i = 0; i < 4; ++i) { a[i][0] = 0.f; a[i][1] = 0.f; }
        #pragma unroll 4
        for (int kk = 0; kk < 64; ++kk) {   // (U*B)[r][c] = sum_k U[k][r] B[k][c] (U symm)
            const float4 u4 = *(const float4*)&sU[kk * 64 + f0];
            const float2 b2 = *(const float2*)&bcur[kk * 64 + g2];
            const float ua[4] = {u4.x, u4.y, u4.z, u4.w};
            #pragma unroll
            for (int i = 0; i < 4; ++i) {
                a[i][0] = fmaf(ua[i], b2.x, a[i][0]);
                a[i][1] = fmaf(ua[i], b2.y, a[i][1]);
            }
        }
        #pragma unroll
        for (int i = 0; i < 4; ++i)
            #pragma unroll
            for (int j = 0; j < 2; ++j) {
                const float v = 2.f * a[i][j] - rP2[i][j] + ((f0 + i == g2 + j) ? ck : 0.f);
                rP2[i][j] = rP[i][j];
                rP[i][j]  = v;
            }
        #pragma unroll
        for (int i = 0; i < 4; ++i) {
            float2 v; v.x = rP[i][0]; v.y = rP[i][1];
            *(float2*)&bnxt[(f0 + i) * 64 + g2] = v;
        }
        float* t = bcur; bcur = bnxt; bnxt = t;
        __syncthreads();
    }
    {   // final: F = c0 I + U*B1 - B2
        const float c0c = sscal[4];
        float a[4][2];
        #pragma unroll
        for (int i = 0; i < 4; ++i) { a[i][0] = 0.f; a[i][1] = 0.f; }
        #pragma unroll 4
        for (int kk = 0; kk < 64; ++kk) {
            const float4 u4 = *(const float4*)&sU[kk * 64 + f0];
            const float2 b2 = *(const float2*)&bcur[kk * 64 + g2];
            const float ua[4] = {u4.x, u4.y, u4.z, u4.w};
            #pragma unroll
            for (int i = 0; i < 4; ++i) {
                a[i][0] = fmaf(ua[i], b2.x, a[i][0]);
                a[i][1] = fmaf(ua[i], b2.y, a[i][1]);
            }
        }
        #pragma unroll
        for (int i = 0; i < 4; ++i) {
            float2 v;
            v.x = ((f0 + i == g2 + 0) ? c0c : 0.f) + a[i][0] - rP2[i][0];
            v.y = ((f0 + i == g2 + 1) ? c0c : 0.f) + a[i][1] - rP2[i][1];
            *(float2*)&bnxt[(f0 + i) * 64 + g2] = v;
        }
    }
    __syncthreads();
    const float* sF = bnxt;

    // symmetrize + triu vectorization with sqrt(2) off-diagonal scaling
    float* ob = out + (size_t)b * 2080;
    for (int idx = tid; idx < 2080; idx += 512) {
        const double disc = 16641.0 - 8.0 * (double)idx;
        const int i = (int)((129.0 - sqrt(disc)) * 0.5);
        const int Si = i * 64 - (i * (i - 1)) / 2;
        const int j = i + (idx - Si);
        float v = 0.5f * (sF[i * 64 + j] + sF[j * 64 + i]);
        if (i != j) v *= 1.4142135623730951f;
        ob[idx] = v;
    }
}

extern "C" void kernel_launch(void* const* d_in, const int* in_sizes, int n_in,
                              void* d_out, int out_size, void* d_ws, size_t ws_size,
                              hipStream_t stream) {
    const float* x    = (const float*)d_in[0];
    const float* wmat = (const float*)d_in[1];
    float* outp = (float*)d_out;
    float* gws  = (float*)d_ws;                                    // 1024*128*128 f32 = 64 MB
    float* sxws = gws + (size_t)NBATCH * CHUNKS * NCH * NCH;       // 1024*128 f32
    k_gram<<<dim3(NBATCH * CHUNKS), dim3(512), 0, stream>>>(x, gws, sxws);
    k_logm<<<dim3(NBATCH), dim3(512), 0, stream>>>(gws, sxws, wmat, outp);
}

// Round 6
// 751.844 us; speedup vs baseline: 1.0376x; 1.0376x over previous
//
#include <hip/hip_runtime.h>

typedef __attribute__((ext_vector_type(8))) short s8_t;   // 8 bf16 (4 VGPRs) MFMA frag
typedef __attribute__((ext_vector_type(4))) float f4_t;   // MFMA accumulator

#define NBATCH 256
#define NCH    128
#define NT     4096
#define NF     64
#define TT     128            // time tile
#define NIT    (NT / TT)      // 32 tiles
#define LDSK   (TT + 8)       // padded LDS row stride (bf16 elems)
#define CHEB_D 20

static __device__ __forceinline__ unsigned short f32_bf16(float f) {
    unsigned int u = __float_as_uint(f);
    return (unsigned short)((u + 0x7FFFu + ((u >> 16) & 1u)) >> 16);  // RNE
}
static __device__ __forceinline__ float bf16_f32(unsigned short h) {
    return __uint_as_float(((unsigned int)h) << 16);
}

// Single fused kernel: per-batch Gram (bf16 MFMA) -> cov -> matrix log (Chebyshev-
// Clenshaw) -> triu vectorization. Grid 256 (1 block/CU), 512 threads (8 waves).
// LDS phase map (floats):
//   phase1: xl = ushort[2][128*136] = floats [0..17408);  red at [33032..33544)
//   phase2: sG[128][128] @0 (overlays dead xl) -> sC0@0, sU@4096, sB0@8192,
//           sB1@12288, sWt@16384, sM1t@24576, ssx@32768, sp@32896, sred@32960,
//           sscal@33024
__global__ __launch_bounds__(512, 1)
void k_fused(const float* __restrict__ x, const float* __restrict__ wmat,
             float* __restrict__ out) {
    __shared__ __align__(16) float lds[33544];   // 134176 B
    unsigned short* xl = (unsigned short*)lds;
    float* sG   = lds;
    float* sC0  = lds;
    float* sU   = lds + 4096;
    float* sB0  = lds + 8192;
    float* sB1  = lds + 12288;
    float* sWt  = lds + 16384;
    float* sM1t = lds + 24576;
    float* ssx  = lds + 32768;
    float* sp   = lds + 32896;
    float* sred = lds + 32960;
    float* sscal= lds + 33024;
    float* red  = lds + 33032;

    const int tid  = threadIdx.x;
    const int b    = blockIdx.x;
    const int lane = tid & 63;
    const int wv   = tid >> 6;       // wave id 0..7
    const int lrow16 = tid >> 5;     // 0..15 (load row group)
    const int lchunk = tid & 31;     // 0..31 (load column chunk)

    const float* xb = x + (size_t)b * ((size_t)NCH * NT);

    // wave wv owns G rows arow0..arow0+31, cols bcol0..bcol0+63
    const int arow0 = (wv & 3) * 32;
    const int bcol0 = (wv >> 2) * 64;
    const int lrow  = lane & 15;
    const int koff  = (lane >> 4) * 8;

    f4_t acc[2][4];
    #pragma unroll
    for (int i = 0; i < 2; ++i)
        #pragma unroll
        for (int j = 0; j < 4; ++j)
            acc[i][j] = (f4_t){0.f, 0.f, 0.f, 0.f};

    float sxp = 0.f;
    float4 ld[8];

    // ---------------- Phase 1: Gram ----------------
    #pragma unroll
    for (int j = 0; j < 8; ++j) {
        const int r = j * 16 + lrow16;
        ld[j] = *(const float4*)(xb + (size_t)r * NT + lchunk * 4);
    }
    #pragma unroll
    for (int j = 0; j < 8; ++j) {
        const int r = j * 16 + lrow16;
        ushort4 h;
        h.x = f32_bf16(ld[j].x); h.y = f32_bf16(ld[j].y);
        h.z = f32_bf16(ld[j].z); h.w = f32_bf16(ld[j].w);
        *(ushort4*)&xl[r * LDSK + lchunk * 4] = h;
    }
    __syncthreads();

    for (int it = 0; it < NIT; ++it) {
        const int cur = it & 1;
        if (it + 1 < NIT) {   // issue next tile's loads early (hide under MFMA)
            const int t0 = (it + 1) * TT;
            #pragma unroll
            for (int j = 0; j < 8; ++j) {
                const int r = j * 16 + lrow16;
                ld[j] = *(const float4*)(xb + (size_t)r * NT + t0 + lchunk * 4);
            }
        }
        const unsigned short* bufc = xl + cur * (NCH * LDSK);
        #pragma unroll
        for (int ks = 0; ks < TT / 32; ++ks) {
            const int k0 = ks * 32 + koff;
            const s8_t af0 = *(const s8_t*)&bufc[(arow0 + lrow) * LDSK + k0];
            const s8_t af1 = *(const s8_t*)&bufc[(arow0 + 16 + lrow) * LDSK + k0];
            #pragma unroll
            for (int cb = 0; cb < 4; ++cb) {
                const s8_t bf = *(const s8_t*)&bufc[(bcol0 + cb * 16 + lrow) * LDSK + k0];
                acc[0][cb] = __builtin_amdgcn_mfma_f32_16x16x32_bf16(af0, bf, acc[0][cb], 0, 0, 0);
                acc[1][cb] = __builtin_amdgcn_mfma_f32_16x16x32_bf16(af1, bf, acc[1][cb], 0, 0, 0);
            }
        }
        {   // channel-sum partial: thread -> row tid>>2, quarter tid&3
            const unsigned short* rp = &bufc[(tid >> 2) * LDSK + (tid & 3) * 32];
            float s = 0.f;
            #pragma unroll
            for (int q = 0; q < 4; ++q) {
                s8_t v = *(const s8_t*)&rp[q * 8];
                #pragma unroll
                for (int e = 0; e < 8; ++e)
                    s += bf16_f32((unsigned short)v[e]);
            }
            sxp += s;
        }
        if (it + 1 < NIT) {   // convert + stage into the other buffer
            unsigned short* bufn = xl + (cur ^ 1) * (NCH * LDSK);
            #pragma unroll
            for (int j = 0; j < 8; ++j) {
                const int r = j * 16 + lrow16;
                ushort4 h;
                h.x = f32_bf16(ld[j].x); h.y = f32_bf16(ld[j].y);
                h.z = f32_bf16(ld[j].z); h.w = f32_bf16(ld[j].w);
                *(ushort4*)&bufn[r * LDSK + lchunk * 4] = h;
            }
        }
        __syncthreads();
    }

    // issue W loads (hide latency under the G dump): thread -> f = tid&63, kq = tid>>6
    const int wf = tid & 63, wkq = tid >> 6;
    float4 wreg[4];
    #pragma unroll
    for (int q = 0; q < 4; ++q)
        wreg[q] = *(const float4*)(wmat + wf * NCH + wkq * 16 + q * 4);

    // dump accumulators to sG (f32, overlays dead xl); channel partials to red
    {
        const int lrow4 = (lane >> 4) * 4;
        const int lcol  = lane & 15;
        #pragma unroll
        for (int i = 0; i < 2; ++i) {
            const int rbase = arow0 + i * 16 + lrow4;
            #pragma unroll
            for (int cb = 0; cb < 4; ++cb) {
                const int col = bcol0 + cb * 16 + lcol;
                #pragma unroll
                for (int reg = 0; reg < 4; ++reg)
                    sG[(rbase + reg) * NCH + col] = acc[i][cb][reg];
            }
        }
    }
    red[tid] = sxp;
    // W transposed into sWt (region overlapped xl tail; xl dead since last barrier)
    #pragma unroll
    for (int q = 0; q < 4; ++q) {
        const int k0 = wkq * 16 + q * 4;
        sWt[(k0 + 0) * 64 + wf] = wreg[q].x;
        sWt[(k0 + 1) * 64 + wf] = wreg[q].y;
        sWt[(k0 + 2) * 64 + wf] = wreg[q].z;
        sWt[(k0 + 3) * 64 + wf] = wreg[q].w;
    }
    __syncthreads();
    if (tid < NCH)
        ssx[tid] = red[tid * 4] + red[tid * 4 + 1] + red[tid * 4 + 2] + red[tid * 4 + 3];
    __syncthreads();

    // ---------------- Phase 2: cov + logm ----------------
    // M1 = W*G (64x128), stored transposed. Thread: 4 f-rows x 4 c-cols.
    {
        const int f0 = (tid >> 5) * 4, c0 = (tid & 31) * 4;
        float a[4][4];
        #pragma unroll
        for (int i = 0; i < 4; ++i)
            #pragma unroll
            for (int j = 0; j < 4; ++j) a[i][j] = 0.f;
        for (int k = 0; k < NCH; ++k) {
            const float4 w4 = *(const float4*)&sWt[k * 64 + f0];
            const float4 g4 = *(const float4*)&sG[k * NCH + c0];
            const float wa[4] = {w4.x, w4.y, w4.z, w4.w};
            const float ga[4] = {g4.x, g4.y, g4.z, g4.w};
            #pragma unroll
            for (int i = 0; i < 4; ++i)
                #pragma unroll
                for (int j = 0; j < 4; ++j)
                    a[i][j] = fmaf(wa[i], ga[j], a[i][j]);
        }
        #pragma unroll
        for (int j = 0; j < 4; ++j) {
            float4 v; v.x = a[0][j]; v.y = a[1][j]; v.z = a[2][j]; v.w = a[3][j];
            *(float4*)&sM1t[(c0 + j) * 64 + f0] = v;
        }
    }
    if (tid < NF) {   // p = W * sx
        float s = 0.f;
        for (int k = 0; k < NCH; ++k) s = fmaf(sWt[k * 64 + tid], ssx[k], s);
        sp[tid] = s;
    }
    __syncthreads();

    // C0 = (M1*W^T - p p^T / T) / (T-1).  Thread: 4 f-rows x 2 g-cols.
    {
        const int f0 = (tid >> 5) * 4, g2 = (tid & 31) * 2;
        float a[4][2];
        #pragma unroll
        for (int i = 0; i < 4; ++i) { a[i][0] = 0.f; a[i][1] = 0.f; }
        for (int k = 0; k < NCH; ++k) {
            const float4 m4 = *(const float4*)&sM1t[k * 64 + f0];
            const float2 w2 = *(const float2*)&sWt[k * 64 + g2];
            const float ma[4] = {m4.x, m4.y, m4.z, m4.w};
            #pragma unroll
            for (int i = 0; i < 4; ++i) {
                a[i][0] = fmaf(ma[i], w2.x, a[i][0]);
                a[i][1] = fmaf(ma[i], w2.y, a[i][1]);
            }
        }
        const float i4096 = 1.f / 4096.f, i4095 = 1.f / 4095.f;
        #pragma unroll
        for (int i = 0; i < 4; ++i)
            #pragma unroll
            for (int j = 0; j < 2; ++j)
                sC0[(f0 + i) * 64 + (g2 + j)] =
                    (a[i][j] - sp[f0 + i] * sp[g2 + j] * i4096) * i4095;
    }
    __syncthreads();

    if (tid == 0) {                        // mu = trace/64
        float s = 0.f;
        for (int i = 0; i < 64; ++i) s += sC0[i * 65];
        sscal[0] = s * (1.f / 64.f);
    }
    __syncthreads();

    const float mu = sscal[0];
    const float dshift = 0.1f * mu + 1e-4f;   // guaranteed lambda_min lower bound
    for (int i = tid; i < 4096; i += 512) {   // A = 0.45(C0+C0^T) + dshift I  -> sU
        const int r = i >> 6, c = i & 63;
        float v = 0.45f * (sC0[r * 64 + c] + sC0[c * 64 + r]);
        if (r == c) v += dshift;
        sU[i] = v;
    }
    __syncthreads();

    if (tid < 64) {                        // Gershgorin: column abs-sums (A symmetric)
        float s = 0.f;
        for (int j = 0; j < 64; ++j) s += fabsf(sU[j * 64 + tid]);
        sred[tid] = s;
    }
    __syncthreads();
    if (tid == 0) {
        float hi = 0.f;
        for (int i = 0; i < 64; ++i) hi = fmaxf(hi, sred[i]);
        const float lo = dshift;
        hi = fmaxf(hi, lo * 1.02f);
        float wsc = (hi - lo) / (hi + lo);
        wsc = fminf(fmaxf(wsc, 1e-6f), 0.999999f);
        const float zz = fmaxf((1.f - sqrtf(fmaxf(1.f - wsc * wsc, 1e-12f))) / wsc, 1e-12f);
        const float mc = 0.5f * (hi + lo);
        sscal[1] = mc;
        sscal[2] = wsc;
        sscal[3] = zz;
        sscal[4] = logf(mc) - log1pf(zz * zz);  // c0 of the Chebyshev series of log
    }
    __syncthreads();

    {   // U = (A/mc - I)/wsc in place, spectrum in [-1,1]
        const float mc = sscal[1], wsc = sscal[2];
        const float inv_mw = 1.f / (mc * wsc);
        const float inv_w  = 1.f / wsc;
        for (int i = tid; i < 4096; i += 512) {
            const int r = i >> 6, c = i & 63;
            float v = sU[i] * inv_mw;
            if (r == c) v -= inv_w;
            sU[i] = v;
        }
    }
    __syncthreads();

    // Matrix Clenshaw: log(x) = c0 + sum_{k=1..D} 2(-1)^{k+1} z^k/k * T_k(u)
    const int f0 = (tid >> 5) * 4, g2 = (tid & 31) * 2;
    const float zc  = sscal[3];
    const float l2z = log2f(zc);
    float rP[4][2], rP2[4][2];
    {
        const float cd = 2.f * ((CHEB_D & 1) ? 1.f : -1.f) *
                         exp2f((float)CHEB_D * l2z) / (float)CHEB_D;
        #pragma unroll
        for (int i = 0; i < 4; ++i)
            #pragma unroll
            for (int j = 0; j < 2; ++j) {
                rP[i][j]  = (f0 + i == g2 + j) ? cd : 0.f;
                rP2[i][j] = 0.f;
            }
        #pragma unroll
        for (int i = 0; i < 4; ++i) {
            float2 v; v.x = rP[i][0]; v.y = rP[i][1];
            *(float2*)&sB0[(f0 + i) * 64 + g2] = v;
        }
    }
    __syncthreads();

    float* bcur = sB0;
    float* bnxt = sB1;
    for (int k = CHEB_D - 1; k >= 1; --k) {
        const float ck = 2.f * ((k & 1) ? 1.f : -1.f) * exp2f((float)k * l2z) / (float)k;
        float a[4][2];
        #pragma unroll
        for (int i = 0; i < 4; ++i) { a[i][0] = 0.f; a[i][1] = 0.f; }
        #pragma unroll 4
        for (int kk = 0; kk < 64; ++kk) {   // (U*B)[r][c] = sum_k U[k][r] B[k][c] (U symm)
            const float4 u4 = *(const float4*)&sU[kk * 64 + f0];
            const float2 b2 = *(const float2*)&bcur[kk * 64 + g2];
            const float ua[4] = {u4.x, u4.y, u4.z, u4.w};
            #pragma unroll
            for (int i = 0; i < 4; ++i) {
                a[i][0] = fmaf(ua[i], b2.x, a[i][0]);
                a[i][1] = fmaf(ua[i], b2.y, a[i][1]);
            }
        }
        #pragma unroll
        for (int i = 0; i < 4; ++i)
            #pragma unroll
            for (int j = 0; j < 2; ++j) {
                const float v = 2.f * a[i][j] - rP2[i][j] + ((f0 + i == g2 + j) ? ck : 0.f);
                rP2[i][j] = rP[i][j];
                rP[i][j]  = v;
            }
        #pragma unroll
        for (int i = 0; i < 4; ++i) {
            float2 v; v.x = rP[i][0]; v.y = rP[i][1];
            *(float2*)&bnxt[(f0 + i) * 64 + g2] = v;
        }
        float* t = bcur; bcur = bnxt; bnxt = t;
        __syncthreads();
    }
    {   // final: F = c0 I + U*B1 - B2
        const float c0c = sscal[4];
        float a[4][2];
        #pragma unroll
        for (int i = 0; i < 4; ++i) { a[i][0] = 0.f; a[i][1] = 0.f; }
        #pragma unroll 4
        for (int kk = 0; kk < 64; ++kk) {
            const float4 u4 = *(const float4*)&sU[kk * 64 + f0];
            const float2 b2 = *(const float2*)&bcur[kk * 64 + g2];
            const float ua[4] = {u4.x, u4.y, u4.z, u4.w};
            #pragma unroll
            for (int i = 0; i < 4; ++i) {
                a[i][0] = fmaf(ua[i], b2.x, a[i][0]);
                a[i][1] = fmaf(ua[i], b2.y, a[i][1]);
            }
        }
        #pragma unroll
        for (int i = 0; i < 4; ++i) {
            float2 v;
            v.x = ((f0 + i == g2 + 0) ? c0c : 0.f) + a[i][0] - rP2[i][0];
            v.y = ((f0 + i == g2 + 1) ? c0c : 0.f) + a[i][1] - rP2[i][1];
            *(float2*)&bnxt[(f0 + i) * 64 + g2] = v;
        }
    }
    __syncthreads();
    const float* sF = bnxt;

    // symmetrize + triu vectorization with sqrt(2) off-diagonal scaling
    float* ob = out + (size_t)b * 2080;
    for (int idx = tid; idx < 2080; idx += 512) {
        const double disc = 16641.0 - 8.0 * (double)idx;
        const int i = (int)((129.0 - sqrt(disc)) * 0.5);
        const int Si = i * 64 - (i * (i - 1)) / 2;
        const int j = i + (idx - Si);
        float v = 0.5f * (sF[i * 64 + j] + sF[j * 64 + i]);
        if (i != j) v *= 1.4142135623730951f;
        ob[idx] = v;
    }
}

extern "C" void kernel_launch(void* const* d_in, const int* in_sizes, int n_in,
                              void* d_out, int out_size, void* d_ws, size_t ws_size,
                              hipStream_t stream) {
    const float* x    = (const float*)d_in[0];
    const float* wmat = (const float*)d_in[1];
    float* outp = (float*)d_out;
    (void)d_ws; (void)ws_size;
    k_fused<<<dim3(NBATCH), dim3(512), 0, stream>>>(x, wmat, outp);
}